// Round 1
// baseline (95.581 us; speedup 1.0000x reference)
//
#include <hip/hip_runtime.h>

#define BB 8
#define NN 4096
#define HH 256
#define KOUT 1024
#define NC 64     // 63 clusters padded to 64

// ---------------- K1: per-batch cluster-sorted K/V pack ----------------
// One 1024-thread block per batch. LDS hist over 64 cluster bins ->
// wave-0 Kogge-Stone scan -> scatter pre-projected K,V (float4) into
// globally cluster-contiguous order. Kills the per-member binary search,
// the member-index indirection, the x-gather, AND the T^2 projection
// recompute in the attention kernel.
__global__ __launch_bounds__(1024) void k_build(
    const float* __restrict__ x, const int* __restrict__ labels,
    const float* __restrict__ Wk, const float* __restrict__ bk,
    const float* __restrict__ Wv, const float* __restrict__ bv,
    int* __restrict__ cstart,   // [BB][NC] exclusive start within batch
    int* __restrict__ ccount,   // [BB][NC]
    float4* __restrict__ kp,    // [BB][NN] cluster-sorted K (w unused)
    float4* __restrict__ vp)    // [BB][NN] cluster-sorted V (w unused)
{
    int b   = blockIdx.x;
    int tid = threadIdx.x;
    __shared__ int hist[NC], cur[NC];
    if (tid < NC) hist[tid] = 0;
    __syncthreads();

    int ls[4];
#pragma unroll
    for (int i = 0; i < 4; ++i) {
        int l = labels[b * NN + tid + 1024 * i];
        ls[i] = l;
        if (l >= 0) atomicAdd(&hist[l], 1);
    }
    __syncthreads();

    if (tid < NC) {           // wave 0 only
        int v = hist[tid];
        int s = v;
#pragma unroll
        for (int d = 1; d < 64; d <<= 1) {
            int o = __shfl_up(s, d, 64);
            if (tid >= d) s += o;
        }
        int e = s - v;        // exclusive prefix
        cstart[b * NC + tid] = e;
        ccount[b * NC + tid] = v;
        cur[tid] = e;
    }
    __syncthreads();

    // hoist weights (wave-uniform -> scalar loads)
    float a0 = Wk[0], a1 = Wk[1], a2 = Wk[2];
    float a3 = Wk[3], a4 = Wk[4], a5 = Wk[5];
    float a6 = Wk[6], a7 = Wk[7], a8 = Wk[8];
    float kb0 = bk[0], kb1 = bk[1], kb2 = bk[2];
    float g0 = Wv[0], g1 = Wv[1], g2 = Wv[2];
    float g3 = Wv[3], g4 = Wv[4], g5 = Wv[5];
    float g6 = Wv[6], g7 = Wv[7], g8 = Wv[8];
    float vb0 = bv[0], vb1 = bv[1], vb2 = bv[2];

#pragma unroll
    for (int i = 0; i < 4; ++i) {
        int l = ls[i];
        if (l < 0) continue;
        int n = tid + 1024 * i;
        int p = atomicAdd(&cur[l], 1);
        const float* xr = x + (b * NN + n) * 3;
        float x0 = xr[0], x1 = xr[1], x2 = xr[2];
        float4 kk, vv;
        kk.x = kb0 + x0 * a0 + x1 * a1 + x2 * a2;
        kk.y = kb1 + x0 * a3 + x1 * a4 + x2 * a5;
        kk.z = kb2 + x0 * a6 + x1 * a7 + x2 * a8;
        kk.w = 0.f;
        vv.x = vb0 + x0 * g0 + x1 * g1 + x2 * g2;
        vv.y = vb1 + x0 * g3 + x1 * g4 + x2 * g5;
        vv.z = vb2 + x0 * g6 + x1 * g7 + x2 * g8;
        vv.w = 0.f;
        kp[b * NN + p] = kk;
        vp[b * NN + p] = vv;
    }
}

// ---------------- K2: wave-per-row over contiguous pre-projected K/V ----------------
// Inner loop per member: 1 coalesced float4 K-load -> dot -> v_exp_f32 ->
// 1 coalesced float4 V-load -> 4 FMA. Scores bounded (|s| ~< 15) so exp
// without max-shift is float-safe (softmax shift invariance).
__global__ __launch_bounds__(256) void k_attn(
    const float* __restrict__ x, const int* __restrict__ labels,
    const int* __restrict__ cstart, const int* __restrict__ ccount,
    const float4* __restrict__ kp, const float4* __restrict__ vp,
    const float* __restrict__ Wq, const float* __restrict__ bq,
    const float* __restrict__ Wo, const float* __restrict__ bo,
    const float* __restrict__ W1, const float* __restrict__ b1,
    const float* __restrict__ W2, const float* __restrict__ b2,
    float* __restrict__ out)
{
    int row  = (blockIdx.x * 256 + threadIdx.x) >> 6;   // 0 .. B*KOUT-1
    int lane = threadIdx.x & 63;
    int b = row >> 10, n = row & (KOUT - 1);
    int l = labels[b * NN + n];            // wave-uniform

    const float* xr = x + (b * NN + n) * 3;
    float x0 = xr[0], x1 = xr[1], x2 = xr[2];
    float q0 = bq[0] + x0 * Wq[0] + x1 * Wq[1] + x2 * Wq[2];
    float q1 = bq[1] + x0 * Wq[3] + x1 * Wq[4] + x2 * Wq[5];
    float q2 = bq[2] + x0 * Wq[6] + x1 * Wq[7] + x2 * Wq[8];

    float c0 = 0.f, c1 = 0.f, c2 = 0.f;
    if (l >= 0) {
        // fold 1/sqrt(3) and log2(e) into q: exp(s*scale) == exp2(s*scale*log2e)
        const float sl2e = 0.5773502691896258f * 1.4426950408889634f;
        float qs0 = q0 * sl2e, qs1 = q1 * sl2e, qs2 = q2 * sl2e;

        int T    = ccount[b * NC + l];
        int base = b * NN + cstart[b * NC + l];
        float dsum = 0.f;
        int Tpad = (T + 63) & ~63;
        for (int i = lane; i < Tpad; i += 64) {
            bool act = i < T;
            int idx = base + (act ? i : 0);   // clamp: keep lanes executing, valid addr
            float4 kk = kp[idx];
            float sc = qs0 * kk.x + qs1 * kk.y + qs2 * kk.z;
            float w = act ? __builtin_amdgcn_exp2f(sc) : 0.f;
            float4 vv = vp[idx];
            dsum += w; c0 += w * vv.x; c1 += w * vv.y; c2 += w * vv.z;
        }
#pragma unroll
        for (int d = 32; d > 0; d >>= 1) {
            dsum += __shfl_xor(dsum, d, 64);
            c0   += __shfl_xor(c0, d, 64);
            c1   += __shfl_xor(c1, d, 64);
            c2   += __shfl_xor(c2, d, 64);
        }
        float inv = 1.f / dsum;
        c0 *= inv; c1 *= inv; c2 *= inv;
    }

    // out_proj (wave-uniform weights)
    float o0 = bo[0] + c0 * Wo[0] + c1 * Wo[1] + c2 * Wo[2];
    float o1 = bo[1] + c0 * Wo[3] + c1 * Wo[4] + c2 * Wo[5];
    float o2 = bo[2] + c0 * Wo[6] + c1 * Wo[7] + c2 * Wo[8];

    // MLP: 4 hidden units per lane + 3-value wave reduction
    float y0 = 0.f, y1 = 0.f, y2 = 0.f;
#pragma unroll
    for (int t = 0; t < 4; t++) {
        int j = lane + 64 * t;
        float h = fmaxf(W1[j * 3 + 0] * o0 + W1[j * 3 + 1] * o1 + W1[j * 3 + 2] * o2 + b1[j], 0.f);
        y0 += h * W2[j];
        y1 += h * W2[HH + j];
        y2 += h * W2[2 * HH + j];
    }
#pragma unroll
    for (int d = 32; d > 0; d >>= 1) {
        y0 += __shfl_xor(y0, d, 64);
        y1 += __shfl_xor(y1, d, 64);
        y2 += __shfl_xor(y2, d, 64);
    }
    if (lane == 0) {
        out[row * 3 + 0] = y0 + b2[0];
        out[row * 3 + 1] = y1 + b2[1];
        out[row * 3 + 2] = y2 + b2[2];
    }
}

extern "C" void kernel_launch(void* const* d_in, const int* in_sizes, int n_in,
                              void* d_out, int out_size, void* d_ws, size_t ws_size,
                              hipStream_t stream) {
    const float* x      = (const float*)d_in[0];
    const int*   labels = (const int*)d_in[1];
    const float* Wq = (const float*)d_in[2];
    const float* bq = (const float*)d_in[3];
    const float* Wk = (const float*)d_in[4];
    const float* bk = (const float*)d_in[5];
    const float* Wv = (const float*)d_in[6];
    const float* bv = (const float*)d_in[7];
    const float* Wo = (const float*)d_in[8];
    const float* bo = (const float*)d_in[9];
    const float* W1 = (const float*)d_in[10];
    const float* b1 = (const float*)d_in[11];
    const float* W2 = (const float*)d_in[12];
    const float* b2 = (const float*)d_in[13];
    float* out = (float*)d_out;

    // workspace: float4 arrays first (16B alignment), then ints
    float4* kp     = (float4*)d_ws;            // BB*NN
    float4* vp     = kp + BB * NN;             // BB*NN
    int*    cstart = (int*)(vp + BB * NN);     // BB*NC
    int*    ccount = cstart + BB * NC;         // BB*NC

    k_build<<<BB, 1024, 0, stream>>>(x, labels, Wk, bk, Wv, bv,
                                     cstart, ccount, kp, vp);
    k_attn<<<(BB * KOUT * 64) / 256, 256, 0, stream>>>(x, labels, cstart, ccount,
                                                       kp, vp, Wq, bq, Wo, bo,
                                                       W1, b1, W2, b2, out);
}